// Round 8
// baseline (148.254 us; speedup 1.0000x reference)
//
#include <hip/hip_runtime.h>

typedef unsigned short ushort_t;
typedef __attribute__((ext_vector_type(8))) short short8v;
typedef __attribute__((ext_vector_type(4))) float f32x4;
typedef __attribute__((ext_vector_type(2))) __bf16 bf16x2;

// LDS element-offset map (ushort elements), 53248 bytes -> 3 blocks/CU:
//  [0,8704)      x-tile [64][136] -> Q [64][136] (after frag load) -> attn-out
//  [8704,17408)  K      [64][136]
//  [17408,26624) V^T    [128][72] -> per-wave ping-pong P scratch 2x[16][72] x4 waves
#define QOFF   0
#define KOFF   8704
#define AOOFF  0
#define VOFF   17408
#define SMEMSZ 26624

__device__ __forceinline__ ushort_t f2bf(float f) {
  return __builtin_bit_cast(unsigned short, (__bf16)f);   // RNE
}
__device__ __forceinline__ unsigned pack2(float lo, float hi) {
  bf16x2 v; v[0] = (__bf16)lo; v[1] = (__bf16)hi;
  return __builtin_bit_cast(unsigned, v);                  // one v_cvt_pk_bf16_f32
}

__device__ __forceinline__ f32x4 mfma16(short8v a, short8v b, f32x4 c) {
  return __builtin_amdgcn_mfma_f32_16x16x32_bf16(a, b, c, 0, 0, 0);
}

// B-fragment loader: lane supplies W[n][k0..k0+7] (contraction along W's row).
template<bool WS>
__device__ __forceinline__ short8v load_w8(const ushort_t* wsp, const float* wf, int n, int k0) {
  if constexpr (WS) {
    return *reinterpret_cast<const short8v*>(wsp + (size_t)n * 128 + k0);
  } else {
    const float* p = wf + (size_t)n * 128 + k0;
    float4 f0 = *reinterpret_cast<const float4*>(p);
    float4 f1 = *reinterpret_cast<const float4*>(p + 4);
    short8v t;
    t[0] = (short)f2bf(f0.x); t[1] = (short)f2bf(f0.y);
    t[2] = (short)f2bf(f0.z); t[3] = (short)f2bf(f0.w);
    t[4] = (short)f2bf(f1.x); t[5] = (short)f2bf(f1.y);
    t[6] = (short)f2bf(f1.z); t[7] = (short)f2bf(f1.w);
    return t;
  }
}

__global__ void cvt_w(const float* __restrict__ qw, const float* __restrict__ pw,
                      ushort_t* __restrict__ ws) {
  const int i = blockIdx.x * 256 + threadIdx.x;
  if (i < 49152) ws[i] = f2bf(qw[i]);
  if (i < 16384) ws[49152 + i] = f2bf(pw[i]);
}

// launch_bounds(256,2): regalloc ceiling 256 VGPR (no spill; (256,3) forced spills).
// Occupancy is LDS-limited to 3 blocks/CU at 53248 B. Keep VGPR <= 170 (3-wave/SIMD line).
template<bool WS>
__global__ __launch_bounds__(256, 2)
void winattn(const float* __restrict__ xg,
             const float* __restrict__ qw,
             const float* __restrict__ pw,
             const float* __restrict__ pb,
             const ushort_t* __restrict__ wsw,
             float* __restrict__ out) {
  __shared__ ushort_t smem[SMEMSZ];

  const int tid  = threadIdx.x;
  const int wid  = tid >> 6;
  const int lane = tid & 63;
  const int l15  = lane & 15;
  const int quad = lane >> 4;

  const int wb = blockIdx.x;            // 0..2047
  const int b  = wb >> 6;
  const int wh = (wb >> 3) & 7;
  const int ww = wb & 7;
  const int rowbase = (b * 56 + wh * 7) * 56 + ww * 7; // token(i,j) elem base = (rowbase+i*56+j)*128

  const float bias0 = pb[wid * 32 + l15];
  const float bias1 = pb[wid * 32 + 16 + l15];

  // ---- Phase A: x window -> LDS bf16 [64][136] at offset 0, rows 49..63 zeroed ----
  {
    const int tr = tid >> 5;   // 0..7
    const int c4 = tid & 31;   // float4 column
    #pragma unroll
    for (int it = 0; it < 8; ++it) {
      const int t = it * 8 + tr;
      uint2 pk = make_uint2(0u, 0u);
      if (t < 49) {
        const int i = t / 7, j = t - (t / 7) * 7;
        const float4 v = *reinterpret_cast<const float4*>(
            xg + (size_t)(rowbase + i * 56 + j) * 128 + c4 * 4);
        pk.x = pack2(v.x, v.y);
        pk.y = pack2(v.z, v.w);
      }
      *reinterpret_cast<uint2*>(&smem[t * 136 + c4 * 4]) = pk;
    }
  }
  __syncthreads();

  // ---- x -> register A-fragments (then x region is dead; Q overlays it) ----
  short8v a[4][4];
  #pragma unroll
  for (int qi = 0; qi < 4; ++qi)
    #pragma unroll
    for (int ks = 0; ks < 4; ++ks)
      a[qi][ks] = *reinterpret_cast<const short8v*>(
          &smem[(qi * 16 + l15) * 136 + ks * 32 + quad * 8]);
  __syncthreads();   // all waves hold x in regs; [0,8704) reusable for Q

  // ---- Phase B: QKV = xw @ qkv_w^T ; write Q (over x), K row-major, V transposed ----
  #pragma unroll
  for (int pass = 0; pass < 2; ++pass) {
    f32x4 acc[4][3];
    #pragma unroll
    for (int qi = 0; qi < 4; ++qi)
      #pragma unroll
      for (int ni = 0; ni < 3; ++ni)
        acc[qi][ni] = (f32x4){0.f, 0.f, 0.f, 0.f};

    #pragma unroll
    for (int nis = 0; nis < 3; ++nis) {
      const int ni = pass * 3 + nis;
      const int n  = wid * 96 + ni * 16 + l15;
      short8v bf[4];
      #pragma unroll
      for (int ks = 0; ks < 4; ++ks)
        bf[ks] = load_w8<WS>(wsw, qw, n, ks * 32 + quad * 8);
      #pragma unroll
      for (int qi = 0; qi < 4; ++qi)
        #pragma unroll
        for (int ks = 0; ks < 4; ++ks)
          acc[qi][nis] = mfma16(a[qi][ks], bf[ks], acc[qi][nis]);
    }

    #pragma unroll
    for (int nis = 0; nis < 3; ++nis) {
      const int ni    = pass * 3 + nis;
      const int obase = wid * 96 + ni * 16;   // wave-uniform, never straddles 128/256
      if (obase < 256) {
        // Q (cols 0..127 -> offset 0) or K (cols 128..255 -> offset 8704), row-major b16 scatter
        const int colo = ((obase < 128) ? QOFF : (KOFF - 128)) + obase + l15;
        #pragma unroll
        for (int qi = 0; qi < 4; ++qi)
          #pragma unroll
          for (int r = 0; r < 4; ++r)
            smem[colo + (qi * 16 + quad * 4 + r) * 136] = f2bf(acc[qi][nis][r]);
      } else {
        // V transposed: Vt[d][k], 4 consecutive k pack into b64
        const int vrow = obase - 256 + l15;
        #pragma unroll
        for (int qi = 0; qi < 4; ++qi) {
          uint2 pk;
          pk.x = pack2(acc[qi][nis][0], acc[qi][nis][1]);
          pk.y = pack2(acc[qi][nis][2], acc[qi][nis][3]);
          *reinterpret_cast<uint2*>(&smem[VOFF + vrow * 72 + qi * 16 + quad * 4]) = pk;
        }
      }
    }
  }

  // Prefetch proj weights for phase F NOW (L2 latency hides under phase C).
  short8v bfF[2][4];
  #pragma unroll
  for (int ni = 0; ni < 2; ++ni)
    #pragma unroll
    for (int ks = 0; ks < 4; ++ks)
      bfF[ni][ks] = load_w8<WS>(wsw + 49152, pw, wid * 32 + ni * 16 + l15, ks * 32 + quad * 8);

  __syncthreads();

  // ---- Phase C': S^T = K Q^T per head (d=16 zero-padded to K=32);
  //      softmax over kt thread-local + 2 shfl; P -> per-wave PING-PONG LDS
  //      scratch (constant-offset NoAlias -> iterations overlap). ----
  // Thread owns S^T[kt = ki*16+quad*4+r][qt = qi*16+l15].
  const float cexp = 0.3606737602222409f; // SCALE(0.25) * log2(e)

  // Preload V B-frags for BOTH heads, then repurpose V region as P scratch.
  short8v bv[2][2];
  #pragma unroll
  for (int hh = 0; hh < 2; ++hh)
    #pragma unroll
    for (int ks = 0; ks < 2; ++ks)
      bv[hh][ks] = *reinterpret_cast<const short8v*>(
          &smem[VOFF + ((wid * 2 + hh) * 16 + l15) * 72 + ks * 32 + quad * 8]);
  __syncthreads();   // all waves done reading V; VOFF becomes per-wave P scratch

  // Per-wave ping-pong P buffers: 2 x [16 q-rows][72] bf16
  const int pbase = VOFF + wid * 2304;

  f32x4 ov[2][4];
  #pragma unroll
  for (int hh = 0; hh < 2; ++hh) {
    const int h    = wid * 2 + hh;
    const int colb = h * 16 + (quad & 1) * 8;
    const bool act = quad < 2;
    short8v bk[4], aq[4];
    #pragma unroll
    for (int ki = 0; ki < 4; ++ki) {
      short8v v = *reinterpret_cast<const short8v*>(&smem[KOFF + (ki * 16 + l15) * 136 + colb]);
      bk[ki] = act ? v : (short8v)0;
    }
    #pragma unroll
    for (int qi = 0; qi < 4; ++qi) {
      short8v v = *reinterpret_cast<const short8v*>(&smem[QOFF + (qi * 16 + l15) * 136 + colb]);
      aq[qi] = act ? v : (short8v)0;
    }

    #pragma unroll
    for (int qi = 0; qi < 4; ++qi) {
      const int pq = pbase + (qi & 1) * 1152;   // ping-pong

      __builtin_amdgcn_s_setprio(1);
      f32x4 st[4];
      #pragma unroll
      for (int ki = 0; ki < 4; ++ki)
        st[ki] = mfma16(bk[ki], aq[qi], (f32x4){0.f, 0.f, 0.f, 0.f});
      __builtin_amdgcn_s_setprio(0);

      // mask kt = 48 + quad*4 + r >= 49  <=>  !(quad==0 && r==0)
      st[3][0] = (quad == 0) ? st[3][0] : -1e30f;
      st[3][1] = -1e30f; st[3][2] = -1e30f; st[3][3] = -1e30f;

      // softmax over kt (no max-sub; |S*scale*log2e| small, exp2(-3.6e29)=0)
      float p[4][4];
      float sum = 0.f;
      #pragma unroll
      for (int ki = 0; ki < 4; ++ki)
        #pragma unroll
        for (int r = 0; r < 4; ++r) {
          const float e = __builtin_amdgcn_exp2f(st[ki][r] * cexp);
          p[ki][r] = e;
          sum += e;
        }
      sum += __shfl_xor(sum, 16);
      sum += __shfl_xor(sum, 32);
      const float rs = __builtin_amdgcn_rcpf(sum);

      // P[q=l15-row][kt] -> ping-pong scratch, 4x b64 packed writes (ascending kt)
      #pragma unroll
      for (int ki = 0; ki < 4; ++ki) {
        uint2 w;
        w.x = pack2(p[ki][0] * rs, p[ki][1] * rs);
        w.y = pack2(p[ki][2] * rs, p[ki][3] * rs);
        *reinterpret_cast<uint2*>(&smem[pq + l15 * 72 + ki * 16 + quad * 4]) = w;
      }

      // PV A-frags straight back out (same wave; ping-pong breaks WAR chain)
      const short8v ap0 = *reinterpret_cast<const short8v*>(&smem[pq + l15 * 72 + quad * 8]);
      const short8v ap1 = *reinterpret_cast<const short8v*>(&smem[pq + l15 * 72 + 32 + quad * 8]);
      __builtin_amdgcn_s_setprio(1);
      f32x4 acc = mfma16(ap0, bv[hh][0], (f32x4){0.f, 0.f, 0.f, 0.f});
      ov[hh][qi] = mfma16(ap1, bv[hh][1], acc);
      __builtin_amdgcn_s_setprio(0);
    }
  }
  __syncthreads();  // all Q/K reads done before attn-out overlays [0,8704)

  // ---- Phase E: attn-out -> LDS [64][136] at offset 0 ----
  #pragma unroll
  for (int hh = 0; hh < 2; ++hh) {
    const int c = (wid * 2 + hh) * 16 + l15;
    #pragma unroll
    for (int qi = 0; qi < 4; ++qi)
      #pragma unroll
      for (int r = 0; r < 4; ++r)
        smem[AOOFF + (qi * 16 + quad * 4 + r) * 136 + c] = f2bf(ov[hh][qi][r]);
  }
  __syncthreads();

  // ---- Phase F: proj = ao @ proj_w^T + b (weights prefetched), window-reverse store ----
  short8v aa[4][4];
  #pragma unroll
  for (int qi = 0; qi < 4; ++qi)
    #pragma unroll
    for (int ks = 0; ks < 4; ++ks)
      aa[qi][ks] = *reinterpret_cast<const short8v*>(
          &smem[AOOFF + (qi * 16 + l15) * 136 + ks * 32 + quad * 8]);

  f32x4 pacc[4][2];
  #pragma unroll
  for (int qi = 0; qi < 4; ++qi)
    #pragma unroll
    for (int ni = 0; ni < 2; ++ni)
      pacc[qi][ni] = (f32x4){0.f, 0.f, 0.f, 0.f};

  #pragma unroll
  for (int ni = 0; ni < 2; ++ni)
    #pragma unroll
    for (int qi = 0; qi < 4; ++qi)
      #pragma unroll
      for (int ks = 0; ks < 4; ++ks)
        pacc[qi][ni] = mfma16(aa[qi][ks], bfF[ni][ks], pacc[qi][ni]);

  #pragma unroll
  for (int qi = 0; qi < 4; ++qi) {
    #pragma unroll
    for (int r = 0; r < 4; ++r) {
      const int q = qi * 16 + quad * 4 + r;
      if (q < 49) {
        const int i = q / 7, j = q - (q / 7) * 7;
        float* op = out + (size_t)(rowbase + i * 56 + j) * 128 + wid * 32 + l15;
        op[0]  = pacc[qi][0][r] + bias0;
        op[16] = pacc[qi][1][r] + bias1;
      }
    }
  }
}

extern "C" void kernel_launch(void* const* d_in, const int* in_sizes, int n_in,
                              void* d_out, int out_size, void* d_ws, size_t ws_size,
                              hipStream_t stream) {
  const float* x  = (const float*)d_in[0];
  const float* qw = (const float*)d_in[1];
  const float* pw = (const float*)d_in[2];
  const float* pb = (const float*)d_in[3];
  float* out      = (float*)d_out;
  ushort_t* ws    = (ushort_t*)d_ws;

  const bool use_ws = (ws_size >= (size_t)(49152 + 16384) * sizeof(ushort_t));
  if (use_ws) {
    hipLaunchKernelGGL(cvt_w, dim3(192), dim3(256), 0, stream, qw, pw, ws);
    hipLaunchKernelGGL((winattn<true>), dim3(2048), dim3(256), 0, stream,
                       x, qw, pw, pb, ws, out);
  } else {
    hipLaunchKernelGGL((winattn<false>), dim3(2048), dim3(256), 0, stream,
                       x, qw, pw, pb, (const ushort_t*)nullptr, out);
  }
}